// Round 13
// baseline (288.580 us; speedup 1.0000x reference)
//
#include <hip/hip_runtime.h>
#include <math.h>

typedef _Float16 f16x8 __attribute__((ext_vector_type(8)));
typedef _Float16 f16x4 __attribute__((ext_vector_type(4)));
typedef float    f32x4 __attribute__((ext_vector_type(4)));
// may_alias views for the unioned LDS region (state-frags <-> per-wave fp16 zbuf)
typedef f16x8 f16x8_a __attribute__((may_alias));
typedef f16x4 f16x4_a __attribute__((may_alias));
typedef f32x4 f32x4_a __attribute__((may_alias));

#define MSAMP 8       // samples per block; state-rows: r = s*8 + m, r 56..63 pad

__device__ __forceinline__ float tanh_fast(float x) {
    // 1 - 2/(exp(2x)+1); ~1e-6 abs error (verified R7..R12: absmax unchanged)
    const float e = __expf(2.0f * x);
    return 1.0f - 2.0f * __builtin_amdgcn_rcpf(e + 1.0f);
}

// W swizzle, single fp16 (UNCHANGED from R12):
//   off(l,kt,jt,lane,jj) = ((l*8+kt)*16+jt)*512 + lane*8 + jj ; per-l stride 65536
// A-fragments of W^T: lane holds A[j = jt*16+(lane&15)][k = kt*32+(lane>>4)*8+jj]
__global__ void prep_w(const float* __restrict__ W1, const float* __restrict__ W2,
                       const float* __restrict__ W3, _Float16* __restrict__ wsw) {
    const int tid = blockIdx.x * 256 + threadIdx.x;      // 3*8*16*64*8 = 196608
    if (tid >= 3 * 8 * 16 * 64 * 8) return;
    const int j    = tid & 7;
    const int lane = (tid >> 3) & 63;
    const int nt   = (tid >> 9) & 15;
    const int kt   = (tid >> 13) & 7;
    const int l    = tid >> 16;
    const float* W = (l == 0) ? W1 : (l == 1) ? W2 : W3;
    const int k = kt * 32 + (lane >> 4) * 8 + j;
    const int n = nt * 16 + (lane & 15);
    wsw[((size_t)((l * 8 + kt) * 16 + nt)) * 512 + lane * 8 + j] = (_Float16)W[k * 256 + n];
}

// SINGLE-fp16 TRANSPOSED GEMM: D[j][r] = sum_k W^T[j][k]*S^T[k][r], 1 MFMA/k-step.
// States: one fp16 buffer B (32 KB), vec idx = (kt*4 + rt)*64 + lane.
// Wave wv owns jt = wv*4..+3; coupled units = B k-slices {2wv,2wv+1} (8 KB) ->
// per-wave fp16 zbuf aliases exactly those slices:
//   zh(r,jl) = wv*4096 + r*64 + ((jl + 4*(r&15)) & 63)   [halfword units]
// (b64 stores/reads land exactly 4 bank-words/bank = the 8B/lane minimum.)
// K rotation kt=(2wv+2+i)&7, barrier inside K-loop at i==6 (verified R10/R12).
// Butterfly epilogue over jgl via shfl_xor (verified R11/R12).
__global__ __launch_bounds__(256, 4)
void pinn_mfma(const float* __restrict__ X,
               const float* __restrict__ W0, const float* __restrict__ b0,
               const float* __restrict__ b1, const float* __restrict__ b2,
               const float* __restrict__ b3,
               const float* __restrict__ W4, const float* __restrict__ b4,
               const float* __restrict__ lb, const float* __restrict__ ub,
               const _Float16* __restrict__ wsw,
               float* __restrict__ out, int N)
{
    __shared__ __attribute__((aligned(16))) char  smem[32768];   // state frags / zbuf
    __shared__ __attribute__((aligned(16))) float redw[448];     // [ch*56+s*8+m][wv]
    f16x8_a*  BV  = (f16x8_a*)smem;               // vec idx = (kt*4+rt)*64 + lane
    _Float16* zbh = (_Float16*)smem;              // per-wave fp16 zbuf view

    const int t    = threadIdx.x;
    const int s0   = blockIdx.x * MSAMP;
    const int wv   = t >> 6, lane = t & 63;
    const int q    = lane >> 4, c = lane & 15;    // C/D + B-frag coords
    const int jgl  = lane >> 3, m = lane & 7;     // coupling task (unit octet, sample)
    const int jg   = wv * 8 + jgl;                // global unit octet 0..31
    const int kt0  = jg >> 2, lq0 = jg & 3;       // B-frag k coords for jg

    // prologue pad-zero mapping (all 8 kt, by 256 threads): zero r=56..63
    const int vidz0 = ((t >> 5) * 4 + 3) * 64 + ((t >> 3) & 3) * 16 + 8 + (t & 7);
    // per-wave pad-zero mapping (wave's own 2 kt slices, by 64 lanes)
    const int vidzw = (((wv * 2 + (lane >> 5)) * 4 + 3) * 64) + (((lane >> 3) & 3) * 16) + 8 + (lane & 7);
    const f16x8 zvec = {};

    float lbv[3], cv[3];
    #pragma unroll
    for (int k = 0; k < 3; ++k) { lbv[k] = lb[k]; cv[k] = 2.0f / (ub[k] - lbv[k]); }

    // ---------------- layer 0: inputs -> first hidden states (B frags) ----------------
    {
        const int jg0 = t >> 3, m0 = t & 7;       // prologue task mapping (global)
        const int n = s0 + m0;
        float x0 = 0.f, x1 = 0.f, x2 = 0.f;
        if (n < N) { x0 = X[n*3+0]; x1 = X[n*3+1]; x2 = X[n*3+2]; }
        const float h0 = cv[0]*(x0 - lbv[0]) - 1.0f;
        const float h1 = cv[1]*(x1 - lbv[1]) - 1.0f;
        const float h2 = cv[2]*(x2 - lbv[2]) - 1.0f;

        float w0v[8], w1v[8], w2v[8], bv[8];
        *(f32x4*)&w0v[0] = *(const f32x4*)&W0[0*256 + jg0*8];
        *(f32x4*)&w0v[4] = *(const f32x4*)&W0[0*256 + jg0*8 + 4];
        *(f32x4*)&w1v[0] = *(const f32x4*)&W0[1*256 + jg0*8];
        *(f32x4*)&w1v[4] = *(const f32x4*)&W0[1*256 + jg0*8 + 4];
        *(f32x4*)&w2v[0] = *(const f32x4*)&W0[2*256 + jg0*8];
        *(f32x4*)&w2v[4] = *(const f32x4*)&W0[2*256 + jg0*8 + 4];
        *(f32x4*)&bv[0]  = *(const f32x4*)&b0[jg0*8];
        *(f32x4*)&bv[4]  = *(const f32x4*)&b0[jg0*8 + 4];

        float st[7][8];
        #pragma unroll
        for (int jj = 0; jj < 8; ++jj) {
            const float zH  = h0*w0v[jj] + h1*w1v[jj] + h2*w2v[jj] + bv[jj];
            const float zt0 = cv[0]*w0v[jj];
            const float zt1 = cv[1]*w1v[jj];
            const float zt2 = cv[2]*w2v[jj];
            const float h   = tanh_fast(zH);
            const float dd  = 1.0f - h*h;
            const float qq  = -2.0f * h * (zt0 + zt1 + zt2);
            st[0][jj] = h;
            st[1][jj] = dd * zt0; st[2][jj] = dd * zt1; st[3][jj] = dd * zt2;
            st[4][jj] = dd * (qq*zt0); st[5][jj] = dd * (qq*zt1); st[6][jj] = dd * (qq*zt2);
        }
        const int k0a = jg0 >> 2, l0a = jg0 & 3;
        #pragma unroll
        for (int s = 0; s < 7; ++s) {
            const int r = s*8 + m0;
            const int vid = (k0a*4 + (r>>4))*64 + l0a*16 + (r & 15);
            f16x8 vh;
            #pragma unroll
            for (int jj = 0; jj < 8; ++jj) vh[jj] = (_Float16)st[s][jj];
            BV[vid] = vh;
        }
        BV[vidz0] = zvec;     // zero pad rows r = 56..63
    }
    __syncthreads();

    // ---------------- hidden layers: rotated-K GEMM + wave-local coupling ----------------
    #pragma unroll 1
    for (int l = 0; l < 3; ++l) {
        const _Float16* __restrict__ Wb = wsw + (size_t)l * 65536;
        const int ktbase = 2*wv + 2;

        f32x4 acc[4][4];   // [mtj][rt]
        #pragma unroll
        for (int a = 0; a < 4; ++a)
            #pragma unroll
            for (int b = 0; b < 4; ++b) acc[a][b] = (f32x4){0.f, 0.f, 0.f, 0.f};

        #pragma unroll
        for (int i = 0; i < 8; ++i) {
            if (i == 6) __syncthreads();   // all foreign-slice reads done before any
                                           // wave's zbuf can clobber its own slices
            const int kt = (ktbase + i) & 7;
            f16x8 sh[4], wh[4];
            #pragma unroll
            for (int rt = 0; rt < 4; ++rt)
                sh[rt] = BV[(kt*4 + rt)*64 + lane];
            #pragma unroll
            for (int mtj = 0; mtj < 4; ++mtj)
                wh[mtj] = *(const f16x8*)&Wb[(size_t)(kt*16 + wv*4 + mtj)*512 + lane*8];
            #pragma unroll
            for (int mtj = 0; mtj < 4; ++mtj)
                #pragma unroll
                for (int rt = 0; rt < 4; ++rt)
                    acc[mtj][rt] = __builtin_amdgcn_mfma_f32_16x16x32_f16(wh[mtj], sh[rt],
                                                                          acc[mtj][rt], 0, 0, 0);
        }

        // C frags -> wave-local fp16 zbuf (own slices only), ds_write_b64
        #pragma unroll
        for (int mtj = 0; mtj < 4; ++mtj) {
            const int jl = mtj*16 + q*4;
            #pragma unroll
            for (int rt = 0; rt < 4; ++rt) {
                const int r = rt*16 + c;
                const int h = wv*4096 + r*64 + ((jl + 4*(r&15)) & 63);
                f16x4 v;
                #pragma unroll
                for (int e = 0; e < 4; ++e) v[e] = (_Float16)acc[mtj][rt][e];
                *(f16x4_a*)&zbh[h] = v;
            }
        }
        asm volatile("s_waitcnt lgkmcnt(0)" ::: "memory");   // stores visible to own wave

        // coupling: lane owns (jg = wv*8+jgl, sample m)
        {
            const float* __restrict__ bb = (l == 0) ? b1 : (l == 1) ? b2 : b3;
            float bvv[8];
            *(f32x4*)&bvv[0] = *(const f32x4*)&bb[jg*8];
            *(f32x4*)&bvv[4] = *(const f32x4*)&bb[jg*8 + 4];

            float z[7][8];
            #pragma unroll
            for (int s = 0; s < 7; ++s) {
                const int r    = s*8 + m;
                const int base = wv*4096 + r*64;
                const int rot  = 4*(r & 15);
                const f16x4 a = *(const f16x4_a*)&zbh[base + ((jgl*8     + rot) & 63)];
                const f16x4 b = *(const f16x4_a*)&zbh[base + ((jgl*8 + 4 + rot) & 63)];
                #pragma unroll
                for (int e = 0; e < 4; ++e) { z[s][e] = (float)a[e]; z[s][4+e] = (float)b[e]; }
            }
            float stt[7][8];
            #pragma unroll
            for (int jj = 0; jj < 8; ++jj) {
                const float zH  = z[0][jj] + bvv[jj];
                const float zt0 = z[1][jj], zt1 = z[2][jj], zt2 = z[3][jj];
                const float zr0 = z[4][jj], zr1 = z[5][jj], zr2 = z[6][jj];
                const float h   = tanh_fast(zH);
                const float dd  = 1.0f - h*h;
                const float qq  = -2.0f * h * (zt0 + zt1 + zt2);
                stt[0][jj] = h;
                stt[1][jj] = dd * zt0; stt[2][jj] = dd * zt1; stt[3][jj] = dd * zt2;
                stt[4][jj] = dd * (zr0 + qq*zt0);
                stt[5][jj] = dd * (zr1 + qq*zt1);
                stt[6][jj] = dd * (zr2 + qq*zt2);
            }

            if (l < 2) {
                // write next-layer B-frags into wave's OWN k slices (same-wave DS
                // ordering: all z-reads above retire before these writes)
                #pragma unroll
                for (int s = 0; s < 7; ++s) {
                    const int r = s*8 + m;
                    const int vid = (kt0*4 + (r>>4))*64 + lq0*16 + (r & 15);
                    f16x8 vh;
                    #pragma unroll
                    for (int jj = 0; jj < 8; ++jj) vh[jj] = (_Float16)stt[s][jj];
                    BV[vid] = vh;
                }
                BV[vidzw] = zvec;     // re-zero wave's pad rows r=56..63
                __syncthreads();      // B-frags ready for next GEMM
            } else {
                // fused final layer: per-lane partials + in-wave butterfly over jgl
                float w4r[16];
                #pragma unroll
                for (int q4 = 0; q4 < 4; ++q4)
                    *(f32x4*)&w4r[q4*4] = *(const f32x4*)&W4[jg*16 + q4*4];
                float p[2][7];
                #pragma unroll
                for (int s = 0; s < 7; ++s) {
                    float p0 = 0.f, p1 = 0.f;
                    #pragma unroll
                    for (int jj = 0; jj < 8; ++jj) {
                        p0 += stt[s][jj] * w4r[jj*2 + 0];
                        p1 += stt[s][jj] * w4r[jj*2 + 1];
                    }
                    p[0][s] = p0; p[1][s] = p1;
                }
                #pragma unroll
                for (int ch = 0; ch < 2; ++ch) {
                    #pragma unroll
                    for (int s = 0; s < 7; ++s) {
                        float v = p[ch][s];
                        v += __shfl_xor(v, 8);
                        v += __shfl_xor(v, 16);
                        v += __shfl_xor(v, 32);
                        p[ch][s] = v;            // sum over jgl, valid in every lane
                    }
                }
                if (jgl == 0) {
                    #pragma unroll
                    for (int ch = 0; ch < 2; ++ch)
                        #pragma unroll
                        for (int s = 0; s < 7; ++s)
                            redw[(ch*56 + s*8 + m)*4 + wv] = p[ch][s];
                }
                __syncthreads();      // redw fully written
            }
        }
    }

    // ---------------- output: 2 ch x 7 states x 8 samples = 112 tasks ----------------
    if (t < 112) {
        const f32x4 vv = *(const f32x4*)&redw[t*4];   // 4 wave partials
        const float v = vv[0] + vv[1] + vv[2] + vv[3];
        const int ch = t / 56, rem = t % 56, s = rem >> 3, mm = rem & 7;
        const int n = s0 + mm;
        if (n < N) {
            const size_t N2 = (size_t)N * 2, N3 = (size_t)N * 3;
            if (s == 0)      out[(size_t)n*2 + ch] = v + b4[ch];
            else if (s <= 3) out[N2 + (size_t)ch*N3 + (size_t)n*3 + (s-1)] = v;
            else             out[N2 + 2*N3 + (size_t)ch*N3 + (size_t)n*3 + (s-4)] = v;
        }
    }
}

extern "C" void kernel_launch(void* const* d_in, const int* in_sizes, int n_in,
                              void* d_out, int out_size, void* d_ws, size_t ws_size,
                              hipStream_t stream) {
    const float* X  = (const float*)d_in[0];
    const float* W0 = (const float*)d_in[1];
    const float* b0 = (const float*)d_in[2];
    const float* W1 = (const float*)d_in[3];
    const float* b1 = (const float*)d_in[4];
    const float* W2 = (const float*)d_in[5];
    const float* b2 = (const float*)d_in[6];
    const float* W3 = (const float*)d_in[7];
    const float* b3 = (const float*)d_in[8];
    const float* W4 = (const float*)d_in[9];
    const float* b4 = (const float*)d_in[10];
    const float* lb = (const float*)d_in[11];
    const float* ub = (const float*)d_in[12];
    float* out = (float*)d_out;
    _Float16* wsw = (_Float16*)d_ws;   // needs 384 KB

    const int N = in_sizes[0] / 3;

    prep_w<<<768, 256, 0, stream>>>(W1, W2, W3, wsw);

    const int grid = (N + MSAMP - 1) / MSAMP;
    pinn_mfma<<<grid, 256, 0, stream>>>(X, W0, b0, b1, b2, b3, W4, b4, lb, ub,
                                        wsw, out, N);
}

// Round 14
// 192.527 us; speedup vs baseline: 1.4989x; 1.4989x over previous
//
#include <hip/hip_runtime.h>
#include <math.h>

typedef _Float16 f16x8 __attribute__((ext_vector_type(8)));
typedef _Float16 f16x4 __attribute__((ext_vector_type(4)));
typedef float    f32x4 __attribute__((ext_vector_type(4)));
// may_alias views for the unioned LDS region (state-frags <-> per-wave fp16 zbuf)
typedef f16x8 f16x8_a __attribute__((may_alias));
typedef f16x4 f16x4_a __attribute__((may_alias));
typedef f32x4 f32x4_a __attribute__((may_alias));

#define MSAMP 8       // samples per block; state-rows: r = s*8 + m, r 56..63 pad

__device__ __forceinline__ float tanh_fast(float x) {
    // 1 - 2/(exp(2x)+1); ~1e-6 abs error (verified R7..R13: absmax unchanged)
    const float e = __expf(2.0f * x);
    return 1.0f - 2.0f * __builtin_amdgcn_rcpf(e + 1.0f);
}

// W swizzle, single fp16 (UNCHANGED from R12/R13):
//   off(l,kt,jt,lane,jj) = ((l*8+kt)*16+jt)*512 + lane*8 + jj ; per-l stride 65536
// A-fragments of W^T: lane holds A[j = jt*16+(lane&15)][k = kt*32+(lane>>4)*8+jj]
__global__ void prep_w(const float* __restrict__ W1, const float* __restrict__ W2,
                       const float* __restrict__ W3, _Float16* __restrict__ wsw) {
    const int tid = blockIdx.x * 256 + threadIdx.x;      // 3*8*16*64*8 = 196608
    if (tid >= 3 * 8 * 16 * 64 * 8) return;
    const int j    = tid & 7;
    const int lane = (tid >> 3) & 63;
    const int nt   = (tid >> 9) & 15;
    const int kt   = (tid >> 13) & 7;
    const int l    = tid >> 16;
    const float* W = (l == 0) ? W1 : (l == 1) ? W2 : W3;
    const int k = kt * 32 + (lane >> 4) * 8 + j;
    const int n = nt * 16 + (lane & 15);
    wsw[((size_t)((l * 8 + kt) * 16 + nt)) * 512 + lane * 8 + j] = (_Float16)W[k * 256 + n];
}

// SINGLE-fp16 TRANSPOSED GEMM (R13 structure): 1 MFMA/k-step.
// launch_bounds(256,3): VGPR cap ~170 — fits the ~152-reg footprint (64 acc +
// ~88 arch) WITHOUT spilling. R13's (256,4) cap=128 spilled 480 MB/dispatch to
// scratch (FETCH 274 MB / WRITE 206 MB) — that was the whole regression.
// LDS 34.8 KB; occupancy = 3 blocks/CU (VGPR-pinned), 12 waves/CU.
__global__ __launch_bounds__(256, 3)
void pinn_mfma(const float* __restrict__ X,
               const float* __restrict__ W0, const float* __restrict__ b0,
               const float* __restrict__ b1, const float* __restrict__ b2,
               const float* __restrict__ b3,
               const float* __restrict__ W4, const float* __restrict__ b4,
               const float* __restrict__ lb, const float* __restrict__ ub,
               const _Float16* __restrict__ wsw,
               float* __restrict__ out, int N)
{
    __shared__ __attribute__((aligned(16))) char  smem[32768];   // state frags / zbuf
    __shared__ __attribute__((aligned(16))) float redw[448];     // [ch*56+s*8+m][wv]
    f16x8_a*  BV  = (f16x8_a*)smem;               // vec idx = (kt*4+rt)*64 + lane
    _Float16* zbh = (_Float16*)smem;              // per-wave fp16 zbuf view

    const int t    = threadIdx.x;
    const int s0   = blockIdx.x * MSAMP;
    const int wv   = t >> 6, lane = t & 63;
    const int q    = lane >> 4, c = lane & 15;    // C/D + B-frag coords
    const int jgl  = lane >> 3, m = lane & 7;     // coupling task (unit octet, sample)
    const int jg   = wv * 8 + jgl;                // global unit octet 0..31
    const int kt0  = jg >> 2, lq0 = jg & 3;       // B-frag k coords for jg

    // prologue pad-zero mapping (all 8 kt, by 256 threads): zero r=56..63
    const int vidz0 = ((t >> 5) * 4 + 3) * 64 + ((t >> 3) & 3) * 16 + 8 + (t & 7);
    // per-wave pad-zero mapping (wave's own 2 kt slices, by 64 lanes)
    const int vidzw = (((wv * 2 + (lane >> 5)) * 4 + 3) * 64) + (((lane >> 3) & 3) * 16) + 8 + (lane & 7);
    const f16x8 zvec = {};

    float lbv[3], cv[3];
    #pragma unroll
    for (int k = 0; k < 3; ++k) { lbv[k] = lb[k]; cv[k] = 2.0f / (ub[k] - lbv[k]); }

    // ---------------- layer 0: inputs -> first hidden states (B frags) ----------------
    {
        const int jg0 = t >> 3, m0 = t & 7;       // prologue task mapping (global)
        const int n = s0 + m0;
        float x0 = 0.f, x1 = 0.f, x2 = 0.f;
        if (n < N) { x0 = X[n*3+0]; x1 = X[n*3+1]; x2 = X[n*3+2]; }
        const float h0 = cv[0]*(x0 - lbv[0]) - 1.0f;
        const float h1 = cv[1]*(x1 - lbv[1]) - 1.0f;
        const float h2 = cv[2]*(x2 - lbv[2]) - 1.0f;

        float w0v[8], w1v[8], w2v[8], bv[8];
        *(f32x4*)&w0v[0] = *(const f32x4*)&W0[0*256 + jg0*8];
        *(f32x4*)&w0v[4] = *(const f32x4*)&W0[0*256 + jg0*8 + 4];
        *(f32x4*)&w1v[0] = *(const f32x4*)&W0[1*256 + jg0*8];
        *(f32x4*)&w1v[4] = *(const f32x4*)&W0[1*256 + jg0*8 + 4];
        *(f32x4*)&w2v[0] = *(const f32x4*)&W0[2*256 + jg0*8];
        *(f32x4*)&w2v[4] = *(const f32x4*)&W0[2*256 + jg0*8 + 4];
        *(f32x4*)&bv[0]  = *(const f32x4*)&b0[jg0*8];
        *(f32x4*)&bv[4]  = *(const f32x4*)&b0[jg0*8 + 4];

        float st[7][8];
        #pragma unroll
        for (int jj = 0; jj < 8; ++jj) {
            const float zH  = h0*w0v[jj] + h1*w1v[jj] + h2*w2v[jj] + bv[jj];
            const float zt0 = cv[0]*w0v[jj];
            const float zt1 = cv[1]*w1v[jj];
            const float zt2 = cv[2]*w2v[jj];
            const float h   = tanh_fast(zH);
            const float dd  = 1.0f - h*h;
            const float qq  = -2.0f * h * (zt0 + zt1 + zt2);
            st[0][jj] = h;
            st[1][jj] = dd * zt0; st[2][jj] = dd * zt1; st[3][jj] = dd * zt2;
            st[4][jj] = dd * (qq*zt0); st[5][jj] = dd * (qq*zt1); st[6][jj] = dd * (qq*zt2);
        }
        const int k0a = jg0 >> 2, l0a = jg0 & 3;
        #pragma unroll
        for (int s = 0; s < 7; ++s) {
            const int r = s*8 + m0;
            const int vid = (k0a*4 + (r>>4))*64 + l0a*16 + (r & 15);
            f16x8 vh;
            #pragma unroll
            for (int jj = 0; jj < 8; ++jj) vh[jj] = (_Float16)st[s][jj];
            BV[vid] = vh;
        }
        BV[vidz0] = zvec;     // zero pad rows r = 56..63
    }
    __syncthreads();

    // ---------------- hidden layers: rotated-K GEMM + wave-local coupling ----------------
    #pragma unroll 1
    for (int l = 0; l < 3; ++l) {
        const _Float16* __restrict__ Wb = wsw + (size_t)l * 65536;
        const int ktbase = 2*wv + 2;

        f32x4 acc[4][4];   // [mtj][rt]
        #pragma unroll
        for (int a = 0; a < 4; ++a)
            #pragma unroll
            for (int b = 0; b < 4; ++b) acc[a][b] = (f32x4){0.f, 0.f, 0.f, 0.f};

        #pragma unroll
        for (int i = 0; i < 8; ++i) {
            if (i == 6) __syncthreads();   // all foreign-slice reads done before any
                                           // wave's zbuf can clobber its own slices
            const int kt = (ktbase + i) & 7;
            f16x8 sh[4], wh[4];
            #pragma unroll
            for (int rt = 0; rt < 4; ++rt)
                sh[rt] = BV[(kt*4 + rt)*64 + lane];
            #pragma unroll
            for (int mtj = 0; mtj < 4; ++mtj)
                wh[mtj] = *(const f16x8*)&Wb[(size_t)(kt*16 + wv*4 + mtj)*512 + lane*8];
            #pragma unroll
            for (int mtj = 0; mtj < 4; ++mtj)
                #pragma unroll
                for (int rt = 0; rt < 4; ++rt)
                    acc[mtj][rt] = __builtin_amdgcn_mfma_f32_16x16x32_f16(wh[mtj], sh[rt],
                                                                          acc[mtj][rt], 0, 0, 0);
        }

        // C frags -> wave-local fp16 zbuf (own slices only), ds_write_b64
        #pragma unroll
        for (int mtj = 0; mtj < 4; ++mtj) {
            const int jl = mtj*16 + q*4;
            #pragma unroll
            for (int rt = 0; rt < 4; ++rt) {
                const int r = rt*16 + c;
                const int h = wv*4096 + r*64 + ((jl + 4*(r&15)) & 63);
                f16x4 v;
                #pragma unroll
                for (int e = 0; e < 4; ++e) v[e] = (_Float16)acc[mtj][rt][e];
                *(f16x4_a*)&zbh[h] = v;
            }
        }
        asm volatile("s_waitcnt lgkmcnt(0)" ::: "memory");   // stores visible to own wave

        // coupling: lane owns (jg = wv*8+jgl, sample m)
        {
            const float* __restrict__ bb = (l == 0) ? b1 : (l == 1) ? b2 : b3;
            float bvv[8];
            *(f32x4*)&bvv[0] = *(const f32x4*)&bb[jg*8];
            *(f32x4*)&bvv[4] = *(const f32x4*)&bb[jg*8 + 4];

            float z[7][8];
            #pragma unroll
            for (int s = 0; s < 7; ++s) {
                const int r    = s*8 + m;
                const int base = wv*4096 + r*64;
                const int rot  = 4*(r & 15);
                const f16x4 a = *(const f16x4_a*)&zbh[base + ((jgl*8     + rot) & 63)];
                const f16x4 b = *(const f16x4_a*)&zbh[base + ((jgl*8 + 4 + rot) & 63)];
                #pragma unroll
                for (int e = 0; e < 4; ++e) { z[s][e] = (float)a[e]; z[s][4+e] = (float)b[e]; }
            }
            float stt[7][8];
            #pragma unroll
            for (int jj = 0; jj < 8; ++jj) {
                const float zH  = z[0][jj] + bvv[jj];
                const float zt0 = z[1][jj], zt1 = z[2][jj], zt2 = z[3][jj];
                const float zr0 = z[4][jj], zr1 = z[5][jj], zr2 = z[6][jj];
                const float h   = tanh_fast(zH);
                const float dd  = 1.0f - h*h;
                const float qq  = -2.0f * h * (zt0 + zt1 + zt2);
                stt[0][jj] = h;
                stt[1][jj] = dd * zt0; stt[2][jj] = dd * zt1; stt[3][jj] = dd * zt2;
                stt[4][jj] = dd * (zr0 + qq*zt0);
                stt[5][jj] = dd * (zr1 + qq*zt1);
                stt[6][jj] = dd * (zr2 + qq*zt2);
            }

            if (l < 2) {
                // write next-layer B-frags into wave's OWN k slices (same-wave DS
                // ordering: all z-reads above retire before these writes)
                #pragma unroll
                for (int s = 0; s < 7; ++s) {
                    const int r = s*8 + m;
                    const int vid = (kt0*4 + (r>>4))*64 + lq0*16 + (r & 15);
                    f16x8 vh;
                    #pragma unroll
                    for (int jj = 0; jj < 8; ++jj) vh[jj] = (_Float16)stt[s][jj];
                    BV[vid] = vh;
                }
                BV[vidzw] = zvec;     // re-zero wave's pad rows r=56..63
                __syncthreads();      // B-frags ready for next GEMM
            } else {
                // fused final layer: per-lane partials + in-wave butterfly over jgl
                float w4r[16];
                #pragma unroll
                for (int q4 = 0; q4 < 4; ++q4)
                    *(f32x4*)&w4r[q4*4] = *(const f32x4*)&W4[jg*16 + q4*4];
                float p[2][7];
                #pragma unroll
                for (int s = 0; s < 7; ++s) {
                    float p0 = 0.f, p1 = 0.f;
                    #pragma unroll
                    for (int jj = 0; jj < 8; ++jj) {
                        p0 += stt[s][jj] * w4r[jj*2 + 0];
                        p1 += stt[s][jj] * w4r[jj*2 + 1];
                    }
                    p[0][s] = p0; p[1][s] = p1;
                }
                #pragma unroll
                for (int ch = 0; ch < 2; ++ch) {
                    #pragma unroll
                    for (int s = 0; s < 7; ++s) {
                        float v = p[ch][s];
                        v += __shfl_xor(v, 8);
                        v += __shfl_xor(v, 16);
                        v += __shfl_xor(v, 32);
                        p[ch][s] = v;            // sum over jgl, valid in every lane
                    }
                }
                if (jgl == 0) {
                    #pragma unroll
                    for (int ch = 0; ch < 2; ++ch)
                        #pragma unroll
                        for (int s = 0; s < 7; ++s)
                            redw[(ch*56 + s*8 + m)*4 + wv] = p[ch][s];
                }
                __syncthreads();      // redw fully written
            }
        }
    }

    // ---------------- output: 2 ch x 7 states x 8 samples = 112 tasks ----------------
    if (t < 112) {
        const f32x4 vv = *(const f32x4*)&redw[t*4];   // 4 wave partials
        const float v = vv[0] + vv[1] + vv[2] + vv[3];
        const int ch = t / 56, rem = t % 56, s = rem >> 3, mm = rem & 7;
        const int n = s0 + mm;
        if (n < N) {
            const size_t N2 = (size_t)N * 2, N3 = (size_t)N * 3;
            if (s == 0)      out[(size_t)n*2 + ch] = v + b4[ch];
            else if (s <= 3) out[N2 + (size_t)ch*N3 + (size_t)n*3 + (s-1)] = v;
            else             out[N2 + 2*N3 + (size_t)ch*N3 + (size_t)n*3 + (s-4)] = v;
        }
    }
}

extern "C" void kernel_launch(void* const* d_in, const int* in_sizes, int n_in,
                              void* d_out, int out_size, void* d_ws, size_t ws_size,
                              hipStream_t stream) {
    const float* X  = (const float*)d_in[0];
    const float* W0 = (const float*)d_in[1];
    const float* b0 = (const float*)d_in[2];
    const float* W1 = (const float*)d_in[3];
    const float* b1 = (const float*)d_in[4];
    const float* W2 = (const float*)d_in[5];
    const float* b2 = (const float*)d_in[6];
    const float* W3 = (const float*)d_in[7];
    const float* b3 = (const float*)d_in[8];
    const float* W4 = (const float*)d_in[9];
    const float* b4 = (const float*)d_in[10];
    const float* lb = (const float*)d_in[11];
    const float* ub = (const float*)d_in[12];
    float* out = (float*)d_out;
    _Float16* wsw = (_Float16*)d_ws;   // needs 384 KB

    const int N = in_sizes[0] / 3;

    prep_w<<<768, 256, 0, stream>>>(W1, W2, W3, wsw);

    const int grid = (N + MSAMP - 1) / MSAMP;
    pinn_mfma<<<grid, 256, 0, stream>>>(X, W0, b0, b1, b2, b3, W4, b4, lb, ub,
                                        wsw, out, N);
}

// Round 16
// 187.616 us; speedup vs baseline: 1.5381x; 1.0262x over previous
//
#include <hip/hip_runtime.h>
#include <math.h>

typedef _Float16 f16x8 __attribute__((ext_vector_type(8)));
typedef _Float16 f16x4 __attribute__((ext_vector_type(4)));
typedef _Float16 f16x2 __attribute__((ext_vector_type(2)));
typedef float    f32x4 __attribute__((ext_vector_type(4)));
// may_alias views for the unioned LDS region (state-frags <-> per-wave fp16 zbuf)
typedef f16x8 f16x8_a __attribute__((may_alias));
typedef f16x4 f16x4_a __attribute__((may_alias));
typedef f32x4 f32x4_a __attribute__((may_alias));

#define MSAMP 8       // samples per block; state-rows: r = s*8 + m, r 56..63 pad

__device__ __forceinline__ float tanh_fast(float x) {
    // 1 - 2/(exp(2x)+1); ~1e-6 abs error (verified R7..R14: absmax unchanged)
    const float e = __expf(2.0f * x);
    return 1.0f - 2.0f * __builtin_amdgcn_rcpf(e + 1.0f);
}

// v_cvt_pkrtz_f16_f32 returns __fp16x2; bit-cast to our _Float16x2 (same repr)
__device__ __forceinline__ f16x2 pkrtz(float a, float b) {
    return __builtin_bit_cast(f16x2, __builtin_amdgcn_cvt_pkrtz(a, b));
}

__device__ __forceinline__ f16x8 cat4(f16x2 a, f16x2 b, f16x2 c, f16x2 d) {
    const f16x4 lo = __builtin_shufflevector(a, b, 0, 1, 2, 3);
    const f16x4 hi = __builtin_shufflevector(c, d, 0, 1, 2, 3);
    return __builtin_shufflevector(lo, hi, 0, 1, 2, 3, 4, 5, 6, 7);
}

__device__ __forceinline__ f16x8 pack8(const float* v) {   // 4x v_cvt_pkrtz
    return cat4(pkrtz(v[0], v[1]), pkrtz(v[2], v[3]),
                pkrtz(v[4], v[5]), pkrtz(v[6], v[7]));
}

// W swizzle, single fp16 (UNCHANGED from R12..R14):
//   off(l,kt,jt,lane,jj) = ((l*8+kt)*16+jt)*512 + lane*8 + jj ; per-l stride 65536
__global__ void prep_w(const float* __restrict__ W1, const float* __restrict__ W2,
                       const float* __restrict__ W3, _Float16* __restrict__ wsw) {
    const int tid = blockIdx.x * 256 + threadIdx.x;      // 3*8*16*64*8 = 196608
    if (tid >= 3 * 8 * 16 * 64 * 8) return;
    const int j    = tid & 7;
    const int lane = (tid >> 3) & 63;
    const int nt   = (tid >> 9) & 15;
    const int kt   = (tid >> 13) & 7;
    const int l    = tid >> 16;
    const float* W = (l == 0) ? W1 : (l == 1) ? W2 : W3;
    const int k = kt * 32 + (lane >> 4) * 8 + j;
    const int n = nt * 16 + (lane & 15);
    wsw[((size_t)((l * 8 + kt) * 16 + nt)) * 512 + lane * 8 + j] = (_Float16)W[k * 256 + n];
}

// SINGLE-fp16 TRANSPOSED GEMM (R14 structure) + PACKED-fp16 coupling:
// states stored f16 (validated R13/R14); t/r updates computed in v_pk_f16
// (z-reads stay f16, results written without conversion) — only zH/tanh in f32.
// launch_bounds(256,3): VGPR cap ~170, no spill (R13's (256,4)=128 spilled).
__global__ __launch_bounds__(256, 3)
void pinn_mfma(const float* __restrict__ X,
               const float* __restrict__ W0, const float* __restrict__ b0,
               const float* __restrict__ b1, const float* __restrict__ b2,
               const float* __restrict__ b3,
               const float* __restrict__ W4, const float* __restrict__ b4,
               const float* __restrict__ lb, const float* __restrict__ ub,
               const _Float16* __restrict__ wsw,
               float* __restrict__ out, int N)
{
    __shared__ __attribute__((aligned(16))) char  smem[32768];   // state frags / zbuf
    __shared__ __attribute__((aligned(16))) float redw[448];     // [ch*56+s*8+m][wv]
    f16x8_a*  BV  = (f16x8_a*)smem;               // vec idx = (kt*4+rt)*64 + lane
    _Float16* zbh = (_Float16*)smem;              // per-wave fp16 zbuf view

    const int t    = threadIdx.x;
    const int s0   = blockIdx.x * MSAMP;
    const int wv   = t >> 6, lane = t & 63;
    const int q    = lane >> 4, c = lane & 15;    // C/D + B-frag coords
    const int jgl  = lane >> 3, m = lane & 7;     // coupling task (unit octet, sample)
    const int jg   = wv * 8 + jgl;                // global unit octet 0..31
    const int kt0  = jg >> 2, lq0 = jg & 3;       // B-frag k coords for jg

    const int vidz0 = ((t >> 5) * 4 + 3) * 64 + ((t >> 3) & 3) * 16 + 8 + (t & 7);
    const int vidzw = (((wv * 2 + (lane >> 5)) * 4 + 3) * 64) + (((lane >> 3) & 3) * 16) + 8 + (lane & 7);
    const f16x8 zvec = {};

    float lbv[3], cv[3];
    #pragma unroll
    for (int k = 0; k < 3; ++k) { lbv[k] = lb[k]; cv[k] = 2.0f / (ub[k] - lbv[k]); }

    // ---------------- layer 0: inputs -> first hidden states (B frags) ----------------
    {
        const int jg0 = t >> 3, m0 = t & 7;
        const int n = s0 + m0;
        float x0 = 0.f, x1 = 0.f, x2 = 0.f;
        if (n < N) { x0 = X[n*3+0]; x1 = X[n*3+1]; x2 = X[n*3+2]; }
        const float h0 = cv[0]*(x0 - lbv[0]) - 1.0f;
        const float h1 = cv[1]*(x1 - lbv[1]) - 1.0f;
        const float h2 = cv[2]*(x2 - lbv[2]) - 1.0f;

        float w0v[8], w1v[8], w2v[8], bv[8];
        *(f32x4*)&w0v[0] = *(const f32x4*)&W0[0*256 + jg0*8];
        *(f32x4*)&w0v[4] = *(const f32x4*)&W0[0*256 + jg0*8 + 4];
        *(f32x4*)&w1v[0] = *(const f32x4*)&W0[1*256 + jg0*8];
        *(f32x4*)&w1v[4] = *(const f32x4*)&W0[1*256 + jg0*8 + 4];
        *(f32x4*)&w2v[0] = *(const f32x4*)&W0[2*256 + jg0*8];
        *(f32x4*)&w2v[4] = *(const f32x4*)&W0[2*256 + jg0*8 + 4];
        *(f32x4*)&bv[0]  = *(const f32x4*)&b0[jg0*8];
        *(f32x4*)&bv[4]  = *(const f32x4*)&b0[jg0*8 + 4];

        float st[7][8];
        #pragma unroll
        for (int jj = 0; jj < 8; ++jj) {
            const float zH  = h0*w0v[jj] + h1*w1v[jj] + h2*w2v[jj] + bv[jj];
            const float zt0 = cv[0]*w0v[jj];
            const float zt1 = cv[1]*w1v[jj];
            const float zt2 = cv[2]*w2v[jj];
            const float h   = tanh_fast(zH);
            const float dd  = 1.0f - h*h;
            const float qq  = -2.0f * h * (zt0 + zt1 + zt2);
            st[0][jj] = h;
            st[1][jj] = dd * zt0; st[2][jj] = dd * zt1; st[3][jj] = dd * zt2;
            st[4][jj] = dd * (qq*zt0); st[5][jj] = dd * (qq*zt1); st[6][jj] = dd * (qq*zt2);
        }
        const int k0a = jg0 >> 2, l0a = jg0 & 3;
        #pragma unroll
        for (int s = 0; s < 7; ++s) {
            const int r = s*8 + m0;
            BV[(k0a*4 + (r>>4))*64 + l0a*16 + (r & 15)] = pack8(&st[s][0]);
        }
        BV[vidz0] = zvec;     // zero pad rows r = 56..63
    }
    __syncthreads();

    // ---------------- hidden layers: rotated-K GEMM + packed wave-local coupling ----------------
    #pragma unroll 1
    for (int l = 0; l < 3; ++l) {
        const _Float16* __restrict__ Wb = wsw + (size_t)l * 65536;
        const int ktbase = 2*wv + 2;

        f32x4 acc[4][4];   // [mtj][rt]
        #pragma unroll
        for (int a = 0; a < 4; ++a)
            #pragma unroll
            for (int b = 0; b < 4; ++b) acc[a][b] = (f32x4){0.f, 0.f, 0.f, 0.f};

        #pragma unroll
        for (int i = 0; i < 8; ++i) {
            if (i == 6) __syncthreads();   // all foreign-slice reads done before any
                                           // wave's zbuf can clobber its own slices
            const int kt = (ktbase + i) & 7;
            f16x8 sh[4], wh[4];
            #pragma unroll
            for (int rt = 0; rt < 4; ++rt)
                sh[rt] = BV[(kt*4 + rt)*64 + lane];
            #pragma unroll
            for (int mtj = 0; mtj < 4; ++mtj)
                wh[mtj] = *(const f16x8*)&Wb[(size_t)(kt*16 + wv*4 + mtj)*512 + lane*8];
            #pragma unroll
            for (int mtj = 0; mtj < 4; ++mtj)
                #pragma unroll
                for (int rt = 0; rt < 4; ++rt)
                    acc[mtj][rt] = __builtin_amdgcn_mfma_f32_16x16x32_f16(wh[mtj], sh[rt],
                                                                          acc[mtj][rt], 0, 0, 0);
        }

        // C frags -> wave-local fp16 zbuf (own slices only), pk converts + b64 stores
        #pragma unroll
        for (int mtj = 0; mtj < 4; ++mtj) {
            const int jl = mtj*16 + q*4;
            #pragma unroll
            for (int rt = 0; rt < 4; ++rt) {
                const int r = rt*16 + c;
                const int h = wv*4096 + r*64 + ((jl + 4*(r&15)) & 63);
                const f16x2 plo = pkrtz(acc[mtj][rt][0], acc[mtj][rt][1]);
                const f16x2 phi = pkrtz(acc[mtj][rt][2], acc[mtj][rt][3]);
                *(f16x4_a*)&zbh[h] = __builtin_shufflevector(plo, phi, 0, 1, 2, 3);
            }
        }
        asm volatile("s_waitcnt lgkmcnt(0)" ::: "memory");   // stores visible to own wave

        // ---- packed coupling: lane owns (jg, m) ----
        {
            const float* __restrict__ bb = (l == 0) ? b1 : (l == 1) ? b2 : b3;
            float bvv[8];
            *(f32x4*)&bvv[0] = *(const f32x4*)&bb[jg*8];
            *(f32x4*)&bvv[4] = *(const f32x4*)&bb[jg*8 + 4];

            f16x4 zlo[7], zhi[7];
            #pragma unroll
            for (int s = 0; s < 7; ++s) {
                const int r    = s*8 + m;
                const int base = wv*4096 + r*64;
                const int rot  = 4*(r & 15);
                zlo[s] = *(const f16x4_a*)&zbh[base + ((jgl*8     + rot) & 63)];
                zhi[s] = *(const f16x4_a*)&zbh[base + ((jgl*8 + 4 + rot) & 63)];
            }

            // tanh path in f32 (8 values)
            float hf[8];
            #pragma unroll
            for (int jj = 0; jj < 8; ++jj) {
                const float z0 = (jj < 4) ? (float)zlo[0][jj] : (float)zhi[0][jj-4];
                hf[jj] = tanh_fast(z0 + bvv[jj]);
            }

            // packed pairs (p = 0..3 <-> units 2p, 2p+1)
            f16x2 zt2[3][4], zr2[3][4];
            #pragma unroll
            for (int k = 0; k < 3; ++k) {
                zt2[k][0] = __builtin_shufflevector(zlo[1+k], zlo[1+k], 0, 1);
                zt2[k][1] = __builtin_shufflevector(zlo[1+k], zlo[1+k], 2, 3);
                zt2[k][2] = __builtin_shufflevector(zhi[1+k], zhi[1+k], 0, 1);
                zt2[k][3] = __builtin_shufflevector(zhi[1+k], zhi[1+k], 2, 3);
                zr2[k][0] = __builtin_shufflevector(zlo[4+k], zlo[4+k], 0, 1);
                zr2[k][1] = __builtin_shufflevector(zlo[4+k], zlo[4+k], 2, 3);
                zr2[k][2] = __builtin_shufflevector(zhi[4+k], zhi[4+k], 0, 1);
                zr2[k][3] = __builtin_shufflevector(zhi[4+k], zhi[4+k], 2, 3);
            }
            const f16x2 one2 = {(_Float16)1.0f,  (_Float16)1.0f};
            const f16x2 m22  = {(_Float16)-2.0f, (_Float16)-2.0f};
            f16x2 h2[4], dd2[4], qq2[4];
            #pragma unroll
            for (int p = 0; p < 4; ++p) {
                h2[p] = pkrtz(hf[2*p], hf[2*p+1]);
                const f16x2 sz = zt2[0][p] + zt2[1][p] + zt2[2][p];
                dd2[p] = one2 - h2[p]*h2[p];
                qq2[p] = m22 * h2[p] * sz;
            }
            f16x2 t2[3][4], r2[3][4];
            #pragma unroll
            for (int k = 0; k < 3; ++k)
                #pragma unroll
                for (int p = 0; p < 4; ++p) {
                    t2[k][p] = dd2[p] * zt2[k][p];
                    r2[k][p] = dd2[p] * (zr2[k][p] + qq2[p]*zt2[k][p]);
                }

            if (l < 2) {
                // B-frag writes: results already f16, zero conversions
                #pragma unroll
                for (int s = 0; s < 7; ++s) {
                    const int r = s*8 + m;
                    const int vid = (kt0*4 + (r>>4))*64 + lq0*16 + (r & 15);
                    f16x8 v;
                    if (s == 0)      v = cat4(h2[0], h2[1], h2[2], h2[3]);
                    else if (s <= 3) v = cat4(t2[s-1][0], t2[s-1][1], t2[s-1][2], t2[s-1][3]);
                    else             v = cat4(r2[s-4][0], r2[s-4][1], r2[s-4][2], r2[s-4][3]);
                    BV[vid] = v;
                }
                BV[vidzw] = zvec;     // re-zero wave's pad rows r=56..63
                __syncthreads();      // B-frags ready for next GEMM
            } else {
                // fused final layer (once): unpack to f32, W4 contraction + butterfly
                float sttf[7][8];
                #pragma unroll
                for (int jj = 0; jj < 8; ++jj) sttf[0][jj] = hf[jj];
                #pragma unroll
                for (int k = 0; k < 3; ++k)
                    #pragma unroll
                    for (int p = 0; p < 4; ++p) {
                        sttf[1+k][2*p]   = (float)t2[k][p][0];
                        sttf[1+k][2*p+1] = (float)t2[k][p][1];
                        sttf[4+k][2*p]   = (float)r2[k][p][0];
                        sttf[4+k][2*p+1] = (float)r2[k][p][1];
                    }
                float w4r[16];
                #pragma unroll
                for (int q4 = 0; q4 < 4; ++q4)
                    *(f32x4*)&w4r[q4*4] = *(const f32x4*)&W4[jg*16 + q4*4];
                float p[2][7];
                #pragma unroll
                for (int s = 0; s < 7; ++s) {
                    float p0 = 0.f, p1 = 0.f;
                    #pragma unroll
                    for (int jj = 0; jj < 8; ++jj) {
                        p0 += sttf[s][jj] * w4r[jj*2 + 0];
                        p1 += sttf[s][jj] * w4r[jj*2 + 1];
                    }
                    p[0][s] = p0; p[1][s] = p1;
                }
                #pragma unroll
                for (int ch = 0; ch < 2; ++ch) {
                    #pragma unroll
                    for (int s = 0; s < 7; ++s) {
                        float v = p[ch][s];
                        v += __shfl_xor(v, 8);
                        v += __shfl_xor(v, 16);
                        v += __shfl_xor(v, 32);
                        p[ch][s] = v;            // sum over jgl, valid in every lane
                    }
                }
                if (jgl == 0) {
                    #pragma unroll
                    for (int ch = 0; ch < 2; ++ch)
                        #pragma unroll
                        for (int s = 0; s < 7; ++s)
                            redw[(ch*56 + s*8 + m)*4 + wv] = p[ch][s];
                }
                __syncthreads();      // redw fully written
            }
        }
    }

    // ---------------- output: 2 ch x 7 states x 8 samples = 112 tasks ----------------
    if (t < 112) {
        const f32x4 vv = *(const f32x4*)&redw[t*4];   // 4 wave partials
        const float v = vv[0] + vv[1] + vv[2] + vv[3];
        const int ch = t / 56, rem = t % 56, s = rem >> 3, mm = rem & 7;
        const int n = s0 + mm;
        if (n < N) {
            const size_t N2 = (size_t)N * 2, N3 = (size_t)N * 3;
            if (s == 0)      out[(size_t)n*2 + ch] = v + b4[ch];
            else if (s <= 3) out[N2 + (size_t)ch*N3 + (size_t)n*3 + (s-1)] = v;
            else             out[N2 + 2*N3 + (size_t)ch*N3 + (size_t)n*3 + (s-4)] = v;
        }
    }
}

extern "C" void kernel_launch(void* const* d_in, const int* in_sizes, int n_in,
                              void* d_out, int out_size, void* d_ws, size_t ws_size,
                              hipStream_t stream) {
    const float* X  = (const float*)d_in[0];
    const float* W0 = (const float*)d_in[1];
    const float* b0 = (const float*)d_in[2];
    const float* W1 = (const float*)d_in[3];
    const float* b1 = (const float*)d_in[4];
    const float* W2 = (const float*)d_in[5];
    const float* b2 = (const float*)d_in[6];
    const float* W3 = (const float*)d_in[7];
    const float* b3 = (const float*)d_in[8];
    const float* W4 = (const float*)d_in[9];
    const float* b4 = (const float*)d_in[10];
    const float* lb = (const float*)d_in[11];
    const float* ub = (const float*)d_in[12];
    float* out = (float*)d_out;
    _Float16* wsw = (_Float16*)d_ws;   // needs 384 KB

    const int N = in_sizes[0] / 3;

    prep_w<<<768, 256, 0, stream>>>(W1, W2, W3, wsw);

    const int grid = (N + MSAMP - 1) / MSAMP;
    pinn_mfma<<<grid, 256, 0, stream>>>(X, W0, b0, b1, b2, b3, W4, b4, lb, ub,
                                        wsw, out, N);
}